// Round 1
// baseline (466.742 us; speedup 1.0000x reference)
//
#include <hip/hip_runtime.h>
#include <math.h>

#define NSEG 8192
#define D 32
#define EPSF 1e-10f
#define ROWS_CAP 512
#define BLK 256

// ---------------------------------------------------------------------------
// seg_start[s] = first row index i with batch[i] >= s  (batch is sorted).
// seg_start has NSEG+1 entries; seg_start[NSEG] = N. Lives in d_ws.
// ---------------------------------------------------------------------------
__global__ void init_starts_kernel(int* __restrict__ seg_start, int N) {
    int s = blockIdx.x * blockDim.x + threadIdx.x;
    if (s <= NSEG) seg_start[s] = N;   // default: empty tail segments
}

__global__ void find_starts_kernel(const int* __restrict__ batch,
                                   int* __restrict__ seg_start, int N) {
    int i = blockIdx.x * blockDim.x + threadIdx.x;
    if (i >= N) return;
    int b = batch[i];
    int prev = (i == 0) ? -1 : batch[i - 1];
    // almost always 0 or 1 iterations (segments are dense)
    for (int s = prev + 1; s <= b; ++s) seg_start[s] = i;
}

// ---------------------------------------------------------------------------
// float4 helpers
// ---------------------------------------------------------------------------
__device__ __forceinline__ float4 f4max(float4 a, float4 b) {
    return make_float4(fmaxf(a.x, b.x), fmaxf(a.y, b.y),
                       fmaxf(a.z, b.z), fmaxf(a.w, b.w));
}
__device__ __forceinline__ float4 f4add(float4 a, float4 b) {
    return make_float4(a.x + b.x, a.y + b.y, a.z + b.z, a.w + b.w);
}
__device__ __forceinline__ float4 shfl_xor_f4(float4 v, int mask) {
    return make_float4(__shfl_xor(v.x, mask, 64), __shfl_xor(v.y, mask, 64),
                       __shfl_xor(v.z, mask, 64), __shfl_xor(v.w, mask, 64));
}

// ---------------------------------------------------------------------------
// One block per segment. Thread t handles col-group cg = t&7 (4 floats) and
// row-groups rg = t>>3, t>>3 + 32, ... Fully coalesced float4 global access
// (each wave touches 8 consecutive rows = 1 KB contiguous).
// xbuf is a per-thread LDS spill: each entry is written and read by the SAME
// thread, so no barriers needed around it — only the reduction scratch.
// ---------------------------------------------------------------------------
__global__ __launch_bounds__(BLK, 2) void seg_softmax_kernel(
    const float* __restrict__ x, const int* __restrict__ seg_start,
    float* __restrict__ out)
{
    __shared__ float4 xbuf[ROWS_CAP * (D / 4)];   // 64 KB
    __shared__ float4 red[4 * (D / 4)];           // [wave][colgrp], 512 B

    const int s     = blockIdx.x;
    const int start = seg_start[s];
    const int end   = seg_start[s + 1];
    const int len   = end - start;
    if (len <= 0) return;   // empty segment: nothing to write

    const int tid  = (int)threadIdx.x;
    const int cg   = tid & 7;     // col group (4 floats)
    const int rg   = tid >> 3;    // row group 0..31
    const int wave = tid >> 6;    // 0..3
    const int lane = tid & 63;

    const float4* __restrict__ xin  = (const float4*)(x   + (size_t)start * D);
    float4* __restrict__       outv = (float4*)      (out + (size_t)start * D);

    const float4 neg_inf4 = make_float4(-INFINITY, -INFINITY, -INFINITY, -INFINITY);

    if (len <= ROWS_CAP) {
        // ---- pass 1: global -> LDS, column max ----
        float4 lmax = neg_inf4;
        for (int r = rg; r < len; r += 32) {
            float4 v = xin[r * 8 + cg];
            xbuf[r * 8 + cg] = v;
            lmax = f4max(lmax, v);
        }
        lmax = f4max(lmax, shfl_xor_f4(lmax, 8));
        lmax = f4max(lmax, shfl_xor_f4(lmax, 16));
        lmax = f4max(lmax, shfl_xor_f4(lmax, 32));
        if (lane < 8) red[wave * 8 + cg] = lmax;
        __syncthreads();
        float4 cmax = f4max(f4max(red[0 * 8 + cg], red[1 * 8 + cg]),
                            f4max(red[2 * 8 + cg], red[3 * 8 + cg]));
        __syncthreads();   // protect red[] reuse

        // ---- pass 2: exp in place (LDS), column sum ----
        float4 lsum = make_float4(0.f, 0.f, 0.f, 0.f);
        for (int r = rg; r < len; r += 32) {
            float4 v = xbuf[r * 8 + cg];
            float4 e;
            e.x = __expf(v.x - cmax.x);
            e.y = __expf(v.y - cmax.y);
            e.z = __expf(v.z - cmax.z);
            e.w = __expf(v.w - cmax.w);
            xbuf[r * 8 + cg] = e;
            lsum = f4add(lsum, e);
        }
        lsum = f4add(lsum, shfl_xor_f4(lsum, 8));
        lsum = f4add(lsum, shfl_xor_f4(lsum, 16));
        lsum = f4add(lsum, shfl_xor_f4(lsum, 32));
        if (lane < 8) red[wave * 8 + cg] = lsum;
        __syncthreads();
        float4 csum = f4add(f4add(red[0 * 8 + cg], red[1 * 8 + cg]),
                            f4add(red[2 * 8 + cg], red[3 * 8 + cg]));
        float4 rnorm = make_float4(1.f / (csum.x + EPSF), 1.f / (csum.y + EPSF),
                                   1.f / (csum.z + EPSF), 1.f / (csum.w + EPSF));

        // ---- pass 3: scale + store ----
        for (int r = rg; r < len; r += 32) {
            float4 e = xbuf[r * 8 + cg];
            e.x *= rnorm.x; e.y *= rnorm.y; e.z *= rnorm.z; e.w *= rnorm.w;
            outv[r * 8 + cg] = e;
        }
    } else {
        // ---- fallback for oversized segments (correctness only; with this
        // input max segment ~310 rows, so this path should never run) ----
        float4 lmax = neg_inf4;
        for (int r = rg; r < len; r += 32)
            lmax = f4max(lmax, xin[r * 8 + cg]);
        lmax = f4max(lmax, shfl_xor_f4(lmax, 8));
        lmax = f4max(lmax, shfl_xor_f4(lmax, 16));
        lmax = f4max(lmax, shfl_xor_f4(lmax, 32));
        if (lane < 8) red[wave * 8 + cg] = lmax;
        __syncthreads();
        float4 cmax = f4max(f4max(red[0 * 8 + cg], red[1 * 8 + cg]),
                            f4max(red[2 * 8 + cg], red[3 * 8 + cg]));
        __syncthreads();

        float4 lsum = make_float4(0.f, 0.f, 0.f, 0.f);
        for (int r = rg; r < len; r += 32) {
            float4 v = xin[r * 8 + cg];
            float4 e;
            e.x = __expf(v.x - cmax.x);
            e.y = __expf(v.y - cmax.y);
            e.z = __expf(v.z - cmax.z);
            e.w = __expf(v.w - cmax.w);
            outv[r * 8 + cg] = e;   // stage exp() in out
            lsum = f4add(lsum, e);
        }
        lsum = f4add(lsum, shfl_xor_f4(lsum, 8));
        lsum = f4add(lsum, shfl_xor_f4(lsum, 16));
        lsum = f4add(lsum, shfl_xor_f4(lsum, 32));
        if (lane < 8) red[wave * 8 + cg] = lsum;
        __syncthreads();
        float4 csum = f4add(f4add(red[0 * 8 + cg], red[1 * 8 + cg]),
                            f4add(red[2 * 8 + cg], red[3 * 8 + cg]));
        float4 rnorm = make_float4(1.f / (csum.x + EPSF), 1.f / (csum.y + EPSF),
                                   1.f / (csum.z + EPSF), 1.f / (csum.w + EPSF));

        for (int r = rg; r < len; r += 32) {
            float4 e = outv[r * 8 + cg];   // same thread wrote it; no fence needed
            e.x *= rnorm.x; e.y *= rnorm.y; e.z *= rnorm.z; e.w *= rnorm.w;
            outv[r * 8 + cg] = e;
        }
    }
}

// ---------------------------------------------------------------------------
extern "C" void kernel_launch(void* const* d_in, const int* in_sizes, int n_in,
                              void* d_out, int out_size, void* d_ws, size_t ws_size,
                              hipStream_t stream) {
    const int*   batch = (const int*)d_in[0];
    const float* x     = (const float*)d_in[1];
    float*       out   = (float*)d_out;
    const int    N     = in_sizes[0];

    int* seg_start = (int*)d_ws;   // (NSEG+1) ints; re-initialized every call

    init_starts_kernel<<<(NSEG + 1 + 255) / 256, 256, 0, stream>>>(seg_start, N);
    find_starts_kernel<<<(N + 255) / 256, 256, 0, stream>>>(batch, seg_start, N);
    seg_softmax_kernel<<<NSEG, BLK, 0, stream>>>(x, seg_start, out);
}